// Round 6
// baseline (346.920 us; speedup 1.0000x reference)
//
#include <hip/hip_runtime.h>

// GAT aggregate, two-phase: N=100000, K=16, D=128, DOUT=128, fp32.
//   Phase 1 (ctx_kernel):  ctx[n] = softmax(<self_n,[neigh_n;self_n]>) . [neigh_n;self_n]
//                          -> written into d_out
//   Phase 2 (mlp_kernel):  d_out[n] = relu(ctx[n] @ W), in place (R5-proven).
//
// Phase-1 R6 restructure: half-wave pair reduction. Lanes 0-31 own neighbor
// row 2j, lanes 32-63 own row 2j+1; each lane holds dims 4q..4q+3 (q=lane&31)
// as float4 (1KB fully-coalesced per load instr). A 5-step shfl_xor butterfly
// within each 32-lane half reduces TWO dot products at once; one shfl_xor(32)
// exchanges them. DS ops/node: 102 -> 57, VMEM instrs 17 -> 9.
//
// NOTE: __launch_bounds__ arg2 observed CUDA-style (min BLOCKS/CU) on this
// toolchain (R2: (512,4) -> 64-VGPR cap + catastrophic spill).

constexpr int K    = 16;
constexpr int D    = 128;
constexpr int DOUT = 128;
constexpr int NPW  = 8;   // nodes per wave-iteration in phase 2

// ---------------- Phase 1: attention context (no LDS, no W) ----------------
__launch_bounds__(256, 4)
__global__ void ctx_kernel(const float* __restrict__ self_vecs,
                           const float* __restrict__ neigh_vecs,
                           float* __restrict__ io,
                           int n_nodes, int total_waves) {
    const int lane = threadIdx.x & 63;
    const int h    = lane >> 5;   // half: 0 -> even rows, 1 -> odd rows
    const int q    = lane & 31;   // owns dims 4q..4q+3
    const int wave = blockIdx.x * (blockDim.x >> 6) + (threadIdx.x >> 6);

    for (int n = wave; n < n_nodes; n += total_waves) {
        // ---- loads: 8 row-pairs (float4/lane, 1KB coalesced each) + self ----
        const float4* nb = (const float4*)(neigh_vecs + (size_t)n * (K * D));
        float4 v[8];
        #pragma unroll
        for (int j = 0; j < 8; ++j)
            v[j] = nb[(2 * j + h) * 32 + q];
        const float4 sv = ((const float4*)(self_vecs + (size_t)n * D))[q];

        // ---- self score: identical partials in both halves -> 5-step reduce ----
        float ps = sv.x * sv.x + sv.y * sv.y + sv.z * sv.z + sv.w * sv.w;
        #pragma unroll
        for (int off = 1; off <= 16; off <<= 1) ps += __shfl_xor(ps, off);

        float m    = ps;                       // running max (self score)
        float ssum = 1.f;                      // e^(s_self - m) = 1
        // self contribution assigned to half 0 only (halves are summed later)
        float4 cx = h ? make_float4(0.f, 0.f, 0.f, 0.f) : sv;

        #pragma unroll
        for (int j = 0; j < 8; ++j) {
            // two dots at once: half h reduces row 2j+h
            float p = sv.x * v[j].x + sv.y * v[j].y + sv.z * v[j].z + sv.w * v[j].w;
            #pragma unroll
            for (int off = 1; off <= 16; off <<= 1) p += __shfl_xor(p, off);
            const float o  = __shfl_xor(p, 32);   // other half's score
            const float se = h ? o : p;           // score of row 2j
            const float so = h ? p : o;           // score of row 2j+1

            // online softmax update with the pair
            const float mn = fmaxf(m, fmaxf(se, so));
            const float sc = __expf(m - mn);
            const float ee = __expf(se - mn);
            const float eo = __expf(so - mn);
            ssum = ssum * sc + ee + eo;
            const float ew = h ? eo : ee;         // weight of the row THIS lane owns
            cx.x = cx.x * sc + ew * v[j].x;
            cx.y = cx.y * sc + ew * v[j].y;
            cx.z = cx.z * sc + ew * v[j].z;
            cx.w = cx.w * sc + ew * v[j].w;
            m = mn;
        }

        // ---- combine halves (4 DS ops), normalize, write dims 4q..4q+3 ----
        cx.x += __shfl_xor(cx.x, 32);
        cx.y += __shfl_xor(cx.y, 32);
        cx.z += __shfl_xor(cx.z, 32);
        cx.w += __shfl_xor(cx.w, 32);
        const float inv = 1.f / ssum;
        if (h == 0)
            ((float4*)(io + (size_t)n * D))[q] =
                make_float4(cx.x * inv, cx.y * inv, cx.z * inv, cx.w * inv);
    }
}

// ---------------- Phase 2: in-place row MLP with relu (R5-proven) ----------------
__launch_bounds__(256, 2)
__global__ void mlp_kernel(const float* __restrict__ W,
                           float* __restrict__ io,
                           int n_nodes, int total_waves) {
    // Interleaved W: float4 slot s = p*64 + l holds
    //   { W[2p][2l], W[2p][2l+1], W[2p+1][2l], W[2p+1][2l+1] }
    __shared__ float Ws[D * DOUT];  // 64 KiB -> 2 blocks/CU

    const int tid = threadIdx.x;
    for (int sI = tid; sI < (D * DOUT) / 4; sI += blockDim.x) {
        const int p = sI >> 6;
        const int l = sI & 63;
        const float* r0 = W + (size_t)(2 * p) * DOUT + 2 * l;
        const float2 a = *(const float2*)r0;
        const float2 b = *(const float2*)(r0 + DOUT);
        ((float4*)Ws)[sI] = make_float4(a.x, a.y, b.x, b.y);
    }
    __syncthreads();

    const int lane = tid & 63;
    const int wave = blockIdx.x * (blockDim.x >> 6) + (tid >> 6);

    for (int base = wave * NPW; base < n_nodes; base += total_waves * NPW) {
        float a0[NPW], a1[NPW];
        #pragma unroll
        for (int j = 0; j < NPW; ++j) { a0[j] = 0.f; a1[j] = 0.f; }

        #pragma unroll 8
        for (int p = 0; p < D / 2; ++p) {
            const float4 w = ((const float4*)Ws)[p * 64 + lane];
            #pragma unroll
            for (int j = 0; j < NPW; ++j) {
                const int n = (base + j < n_nodes) ? base + j : n_nodes - 1;
                const float2 c = *(const float2*)(io + (size_t)n * D + 2 * p);
                a0[j] += c.x * w.x + c.y * w.z;
                a1[j] += c.x * w.y + c.y * w.w;
            }
        }
        #pragma unroll
        for (int j = 0; j < NPW; ++j) {
            if (base + j < n_nodes)
                *(float2*)(io + (size_t)(base + j) * DOUT + 2 * lane) =
                    make_float2(fmaxf(a0[j], 0.f), fmaxf(a1[j], 0.f));
        }
    }
}

extern "C" void kernel_launch(void* const* d_in, const int* in_sizes, int n_in,
                              void* d_out, int out_size, void* d_ws, size_t ws_size,
                              hipStream_t stream) {
    const float* self_vecs = (const float*)d_in[0];
    const float* neigh     = (const float*)d_in[1];
    const float* W         = (const float*)d_in[2];
    float* io = (float*)d_out;

    const int n_nodes = in_sizes[0] / D;  // 100000

    // Phase 1: grid-stride, one node per wave-iteration
    {
        const int tpb = 256;      // 4 waves
        const int blocks = 2048;  // ~8 blocks/CU, waves stay resident
        const int total_waves = blocks * (tpb / 64);
        ctx_kernel<<<dim3(blocks), dim3(tpb), 0, stream>>>(
            self_vecs, neigh, io, n_nodes, total_waves);
    }
    // Phase 2: grid-stride, 8 nodes per wave-iteration
    {
        const int tpb = 256;     // 4 waves
        const int blocks = 512;  // 2 blocks/CU x 256 CU
        const int total_waves = blocks * (tpb / 64);
        mlp_kernel<<<dim3(blocks), dim3(tpb), 0, stream>>>(
            W, io, n_nodes, total_waves);
    }
}

// Round 7
// 334.706 us; speedup vs baseline: 1.0365x; 1.0365x over previous
//
#include <hip/hip_runtime.h>

// GAT aggregate, two-phase: N=100000, K=16, D=128, DOUT=128, fp32.
//   Phase 1 (ctx_kernel):  ctx[n] = softmax(<self_n,[neigh_n;self_n]>) . [neigh_n;self_n]
//                          -> written into d_out   (EXACT R5 structure, proven best)
//   Phase 2 (mlp_kernel):  d_out[n] = relu(ctx[n] @ W), in place.
//
// R7 change is phase 2 ONLY (A/B isolation): 512-thread blocks lift occupancy
// from 2 waves/SIMD to 4 (64KiB W tile still allows 2 blocks/CU), and float4
// uniform ctx loads halve the VMEM instruction count of the inner loop.
// Phase-2 theory: latency-bound on wave-uniform ctx loads at 2 waves/SIMD.
//
// NOTE: __launch_bounds__ arg2 observed CUDA-style (min BLOCKS/CU) on this
// toolchain (R2: (512,4) -> 64-VGPR cap + catastrophic spill). (512,2) -> cap
// >=128 under either interpretation.

constexpr int K    = 16;
constexpr int D    = 128;
constexpr int DOUT = 128;
constexpr int NPW  = 8;   // nodes per wave-iteration in phase 2

__device__ __forceinline__ float wave_allsum(float x) {
    #pragma unroll
    for (int off = 32; off; off >>= 1)
        x += __shfl_xor(x, off);
    return x;
}

// ---------------- Phase 1: attention context (no LDS, no W) — R5 exact ----------------
__launch_bounds__(256, 4)
__global__ void ctx_kernel(const float* __restrict__ self_vecs,
                           const float* __restrict__ neigh_vecs,
                           float* __restrict__ io,
                           int n_nodes) {
    const int lane = threadIdx.x & 63;
    const int n = (int)((blockIdx.x * blockDim.x + threadIdx.x) >> 6);
    if (n >= n_nodes) return;

    // 17 coalesced float2 loads per lane (dims 2l, 2l+1), all in flight
    const float* nbp = neigh_vecs + (size_t)n * (K * D) + 2 * lane;
    float2 v[K];
    #pragma unroll
    for (int k = 0; k < K; ++k) v[k] = *(const float2*)(nbp + (size_t)k * D);
    const float2 s = *(const float2*)(self_vecs + (size_t)n * D + 2 * lane);

    // online softmax + context, initialized from the self term (R4/R5-verified)
    float m = wave_allsum(s.x * s.x + s.y * s.y);
    float sum = 1.f, cx = s.x, cy = s.y;
    #pragma unroll
    for (int k = 0; k < K; ++k) {
        const float d  = wave_allsum(s.x * v[k].x + s.y * v[k].y);
        const float mn = fmaxf(m, d);
        const float sc = __expf(m - mn);
        const float e  = __expf(d - mn);
        sum = sum * sc + e;
        cx  = cx * sc + e * v[k].x;
        cy  = cy * sc + e * v[k].y;
        m = mn;
    }
    const float inv = 1.f / sum;
    *(float2*)(io + (size_t)n * D + 2 * lane) = make_float2(cx * inv, cy * inv);
}

// ---------------- Phase 2: in-place row MLP with relu ----------------
__launch_bounds__(512, 2)
__global__ void mlp_kernel(const float* __restrict__ W,
                           float* __restrict__ io,
                           int n_nodes, int total_waves) {
    // Interleaved W: float4 slot s = p*64 + l holds
    //   { W[2p][2l], W[2p][2l+1], W[2p+1][2l], W[2p+1][2l+1] }  (R1-verified)
    __shared__ float Ws[D * DOUT];  // 64 KiB -> 2 blocks/CU; 512 thr -> 16 waves/CU

    const int tid = threadIdx.x;
    for (int sI = tid; sI < (D * DOUT) / 4; sI += blockDim.x) {
        const int p = sI >> 6;
        const int l = sI & 63;
        const float* r0 = W + (size_t)(2 * p) * DOUT + 2 * l;
        const float2 a = *(const float2*)r0;
        const float2 b = *(const float2*)(r0 + DOUT);
        ((float4*)Ws)[sI] = make_float4(a.x, a.y, b.x, b.y);
    }
    __syncthreads();

    const int lane = tid & 63;
    const int wave = blockIdx.x * (blockDim.x >> 6) + (tid >> 6);

    for (int base = wave * NPW; base < n_nodes; base += total_waves * NPW) {
        float a0[NPW], a1[NPW];
        #pragma unroll
        for (int j = 0; j < NPW; ++j) { a0[j] = 0.f; a1[j] = 0.f; }

        // two p-steps per float4 ctx load: one uniform 16B load serves dims 2p..2p+3
        #pragma unroll 4
        for (int p = 0; p < D / 2; p += 2) {
            const float4 w0 = ((const float4*)Ws)[p * 64 + lane];
            const float4 w1 = ((const float4*)Ws)[(p + 1) * 64 + lane];
            #pragma unroll
            for (int j = 0; j < NPW; ++j) {
                const int n = (base + j < n_nodes) ? base + j : n_nodes - 1;
                const float4 c = *(const float4*)(io + (size_t)n * D + 2 * p);
                a0[j] += c.x * w0.x + c.y * w0.z + c.z * w1.x + c.w * w1.z;
                a1[j] += c.x * w0.y + c.y * w0.w + c.z * w1.y + c.w * w1.w;
            }
        }
        #pragma unroll
        for (int j = 0; j < NPW; ++j) {
            if (base + j < n_nodes)
                *(float2*)(io + (size_t)(base + j) * DOUT + 2 * lane) =
                    make_float2(fmaxf(a0[j], 0.f), fmaxf(a1[j], 0.f));
        }
    }
}

extern "C" void kernel_launch(void* const* d_in, const int* in_sizes, int n_in,
                              void* d_out, int out_size, void* d_ws, size_t ws_size,
                              hipStream_t stream) {
    const float* self_vecs = (const float*)d_in[0];
    const float* neigh     = (const float*)d_in[1];
    const float* W         = (const float*)d_in[2];
    float* io = (float*)d_out;

    const int n_nodes = in_sizes[0] / D;  // 100000

    // Phase 1: one wave per node (R5 exact)
    {
        const int tpb = 256;  // 4 waves
        const int blocks = (n_nodes * 64 + tpb - 1) / tpb;  // 25000
        ctx_kernel<<<dim3(blocks), dim3(tpb), 0, stream>>>(
            self_vecs, neigh, io, n_nodes);
    }
    // Phase 2: grid-stride, 8 nodes per wave-iteration, 512-thr blocks
    {
        const int tpb = 512;     // 8 waves
        const int blocks = 512;  // 2 blocks/CU x 256 CU
        const int total_waves = blocks * (tpb / 64);
        mlp_kernel<<<dim3(blocks), dim3(tpb), 0, stream>>>(
            W, io, n_nodes, total_waves);
    }
}